// Round 13
// baseline (380.380 us; speedup 1.0000x reference)
//
#include <hip/hip_runtime.h>
#include <hip/hip_cooperative_groups.h>
#include <float.h>
#include <math.h>

namespace cg = cooperative_groups;

#define B_ 4
#define L_ 4096
#define H_ 8
#define D_ 64
#define S_ 45      // sample_k == u == 45
#define KC_ 16     // k-chunks for attention pass
#define KCH_ 256   // k per chunk
#define SCALE 0.125f

typedef __attribute__((ext_vector_type(8))) short short8;
typedef __attribute__((ext_vector_type(4))) float float4v;

__device__ __forceinline__ ushort f2bf(float x) {
  unsigned u = __float_as_uint(x);
  return (ushort)((u + 0x7FFFu + ((u >> 16) & 1u)) >> 16);
}

// swizzled ushort index: row-major rows of rowb bytes, 16B slots XORed by row&m
__device__ __forceinline__ int swz_us(int row, int col_b, int rowb, int m) {
  int slot = (col_b >> 4) ^ (row & m);
  return row * (rowb >> 1) + (slot << 3) + ((col_b & 15) >> 1);
}

__device__ __forceinline__ unsigned ordf(float f) {
  unsigned u = __float_as_uint(f);
  return (u & 0x80000000u) ? ~u : (u | 0x80000000u);
}

// ================= kA: 2-head time-phased gather + csum_chunks (R12-proven) ===
// CLOSED: at per-CU vector-memory line-throughput roofline (~23.6M lines,
// ~2.5 cyc/line/CU ~= 100us). Duration invariant to residency/MLP/occupancy.
__global__ __launch_bounds__(256) void kA(
    const float* __restrict__ Q, const float* __restrict__ K,
    const float* __restrict__ V, const int* __restrict__ idxs,
    float* __restrict__ M, float* __restrict__ cs)
{
  int blk = blockIdx.x;
  int grp = blk / 136, within = blk % 136;
  int tid = threadIdx.x;
  int w = tid >> 6, lane = tid & 63;

  if (within >= 128) {
    if (grp >= 64) return;                   // only 512 csum blocks needed
    int cblk = grp * 8 + (within - 128);     // 0..511
    int bh = cblk >> 4, cg = cblk & 15;
    int b = bh >> 3, h = bh & 7;
    int t = lane & 15, rg = lane >> 4;
    int c = cg * 4 + w;
    int l0 = c * 64;
    const float4* V4 = (const float4*)V;
    float4 acc = make_float4(0.f, 0.f, 0.f, 0.f);
    for (int step = 0; step < 16; ++step) {
      int l = l0 + step * 4 + rg;
      float4 v = V4[((size_t)(b * L_ + l) * H_ + h) * 16 + t];
      acc.x += v.x; acc.y += v.y; acc.z += v.z; acc.w += v.w;
    }
    acc.x += __shfl_xor(acc.x, 16, 64); acc.y += __shfl_xor(acc.y, 16, 64);
    acc.z += __shfl_xor(acc.z, 16, 64); acc.w += __shfl_xor(acc.w, 16, 64);
    acc.x += __shfl_xor(acc.x, 32, 64); acc.y += __shfl_xor(acc.y, 32, 64);
    acc.z += __shfl_xor(acc.z, 32, 64); acc.w += __shfl_xor(acc.w, 32, 64);
    if (rg == 0)
      ((float4*)cs)[((size_t)bh * 64 + c) * 16 + t] = acc;
    return;
  }

  // ---- gather ----
  int kblk = grp * 128 + within;        // 0..16383; kblk%8 == blk%8 (XCD pin)
  int phase = kblk >> 13;               // 0: b in {0,1}; 1: b in {2,3}
  int pblk = kblk & 8191;
  int g = pblk & 7;                     // XCD-pinned group within phase
  int b = (g >> 2) + phase * 2;
  int hq = g & 3;                       // head pair hq*2, hq*2+1
  int chunk = pblk >> 3;                // 0..1023
  int l = chunk * 4 + w;                // this wave's query
  int t31 = lane & 31;
  int half = lane >> 5;

  const float4* qp =
      (const float4*)(Q + ((size_t)(b * L_ + l) * H_ + hq * 2) * D_);
  float4 qv = qp[t31];

  int s = lane < S_ ? lane : S_ - 1;
  int idxall = idxs[l * S_ + s];

  float vmax = -FLT_MAX, vsum = 0.f;
  #pragma unroll
  for (int c = 0; c < 3; ++c) {
    int kidx[6];
    #pragma unroll
    for (int jj = 0; jj < 6; ++jj)
      kidx[jj] = __shfl(idxall, (c * 6 + jj) * 2 + half, 64);
    float4 kv[6];
    #pragma unroll
    for (int jj = 0; jj < 6; ++jj)
      kv[jj] = ((const float4*)(K +
          ((size_t)(b * L_ + kidx[jj]) * H_ + hq * 2) * D_))[t31];
    #pragma unroll
    for (int jj = 0; jj < 6; ++jj) {
      float p = qv.x * kv[jj].x;
      p = fmaf(qv.y, kv[jj].y, p);
      p = fmaf(qv.z, kv[jj].z, p);
      p = fmaf(qv.w, kv[jj].w, p);
      p += __shfl_xor(p, 1, 64);
      p += __shfl_xor(p, 2, 64);
      p += __shfl_xor(p, 4, 64);
      p += __shfl_xor(p, 8, 64);
      vmax = fmaxf(vmax, p);
      vsum += p;
    }
  }
  {
    int kidx[5];
    #pragma unroll
    for (int jj = 0; jj < 5; ++jj) {
      int s2 = (18 + jj) * 2 + half;          // 36..45
      kidx[jj] = __shfl(idxall, s2 > 44 ? 44 : s2, 64);
    }
    float4 kv[5];
    #pragma unroll
    for (int jj = 0; jj < 5; ++jj)
      kv[jj] = ((const float4*)(K +
          ((size_t)(b * L_ + kidx[jj]) * H_ + hq * 2) * D_))[t31];
    #pragma unroll
    for (int jj = 0; jj < 5; ++jj) {
      float p = qv.x * kv[jj].x;
      p = fmaf(qv.y, kv[jj].y, p);
      p = fmaf(qv.z, kv[jj].z, p);
      p = fmaf(qv.w, kv[jj].w, p);
      p += __shfl_xor(p, 1, 64);
      p += __shfl_xor(p, 2, 64);
      p += __shfl_xor(p, 4, 64);
      p += __shfl_xor(p, 8, 64);
      bool dup = (jj == 4) && (half == 1);    // sample 45 -> clamped dup
      vmax = fmaxf(vmax, p);
      if (!dup) vsum += p;
    }
  }
  vmax = fmaxf(vmax, __shfl_xor(vmax, 32, 64));
  vsum += __shfl_xor(vsum, 32, 64);
  if ((lane & 15) == 0 && half == 0) {
    int h = hq * 2 + (lane >> 4);
    M[(size_t)(b * H_ + h) * L_ + l] = vmax - vsum * (1.0f / L_);
  }
}

// ================= kT: cooperative tail ========================================
// phase==0 (cooperative, grid 512): P1 { topk(0..31) | scan(32..39) |
//   K-prestage(40..511) } -> grid.sync -> P2 { MFMA attention, all 512 } ->
//   grid.sync -> P3 { cumsum-write (all) + finalize (0..31) }.
// phase==1/2/3 (fallback, separate launches): same bodies, no grid.sync.
__global__ __launch_bounds__(256) void kT(
    const float* __restrict__ Q, const float* __restrict__ K,
    const float* __restrict__ V, const float* __restrict__ M,
    float* __restrict__ cs, int* __restrict__ mtop,
    float* __restrict__ lpart, float* __restrict__ updp,
    float* __restrict__ out, int phase)
{
  __shared__ __align__(16) ushort Ks[256 * 64];   // 32 KB; reused as Vt[64][256]
  __shared__ __align__(16) ushort Qs[48 * 64];    // 6 KB
  __shared__ __align__(16) ushort Ps[48 * 256];   // 24 KB (P1: topk cand overlay)
  __shared__ float lred[4][48];
  __shared__ int   cut[48];

  int blk = blockIdx.x;
  int tid = threadIdx.x;
  int w = tid >> 6, lane = tid & 63;
  bool coop = (phase == 0);

  // kATT role decode (blk in [0,512))
  int kc = blk >> 5;
  int r5 = blk & 31;
  int bh_att = ((r5 & 7) << 2) | (r5 >> 3);   // blk%8 == bh>>2 -> XCD pin
  int b_att = bh_att >> 3, h_att = bh_att & 7;

  // ===== phase 1 =====
  if (coop || phase == 1) {
    if (blk < 32) {
      // ---- topk (R12-proven), cand overlaid on Ps ----
      unsigned long long (*cand)[S_] = (unsigned long long (*)[S_])Ps;
      int bh = blk;
      const float* Mp = M + (size_t)bh * L_;
      unsigned long long key[16];
      #pragma unroll
      for (int j = 0; j < 16; ++j) {
        int gi = w * 1024 + j * 64 + lane;
        key[j] = ((unsigned long long)ordf(Mp[gi]) << 32) | (unsigned)(~gi);
      }
      for (int it = 0; it < S_; ++it) {
        unsigned long long loc = key[0];
        #pragma unroll
        for (int j = 1; j < 16; ++j) loc = key[j] > loc ? key[j] : loc;
        unsigned long long best = loc;
        #pragma unroll
        for (int m = 32; m >= 1; m >>= 1) {
          unsigned long long o = __shfl_xor(best, m, 64);
          best = o > best ? o : best;
        }
        if (loc == best) {
          #pragma unroll
          for (int j = 0; j < 16; ++j) if (key[j] == best) key[j] = 0ull;
        }
        if (lane == 0) cand[w][it] = best;
      }
      __syncthreads();
      if (w == 0) {
        unsigned long long k2[3];
        #pragma unroll
        for (int j = 0; j < 3; ++j) {
          int c = j * 64 + lane;
          k2[j] = (c < 4 * S_) ? cand[c / S_][c % S_] : 0ull;
        }
        for (int it = 0; it < S_; ++it) {
          unsigned long long loc = k2[0];
          loc = k2[1] > loc ? k2[1] : loc;
          loc = k2[2] > loc ? k2[2] : loc;
          unsigned long long best = loc;
          #pragma unroll
          for (int m = 32; m >= 1; m >>= 1) {
            unsigned long long o = __shfl_xor(best, m, 64);
            best = o > best ? o : best;
          }
          if (loc == best) {
            #pragma unroll
            for (int j = 0; j < 3; ++j) if (k2[j] == best) k2[j] = 0ull;
          }
          if (lane == 0) mtop[bh * S_ + it] = (int)(~(unsigned)(best & 0xFFFFFFFFu));
        }
      }
    } else if (blk < 40) {
      // ---- csum scan (R12-proven two-phase reg) ----
      int g = (blk - 32) * 256 + tid;    // 2048 threads total
      int bh = g >> 6, d = g & 63;
      float v[64];
      #pragma unroll
      for (int c = 0; c < 64; ++c) v[c] = cs[((size_t)bh * 64 + c) * D_ + d];
      float run = 0.f;
      #pragma unroll
      for (int c = 0; c < 64; ++c) {
        float a = v[c];
        cs[((size_t)bh * 64 + c) * D_ + d] = run;
        run += a;
      }
    } else if (coop) {
      // ---- K-chunk prestage (hidden under topk) ----
      const float4* kp =
          (const float4*)(K + ((size_t)(b_att * L_ + kc * KCH_ + tid) * H_ + h_att) * D_);
      #pragma unroll
      for (int c = 0; c < 8; ++c) {
        float4 a = kp[2 * c], bb = kp[2 * c + 1];
        uint4 pk;
        pk.x = f2bf(a.x) | ((unsigned)f2bf(a.y) << 16);
        pk.y = f2bf(a.z) | ((unsigned)f2bf(a.w) << 16);
        pk.z = f2bf(bb.x) | ((unsigned)f2bf(bb.y) << 16);
        pk.w = f2bf(bb.z) | ((unsigned)f2bf(bb.w) << 16);
        *(uint4*)&Ks[swz_us(tid, c * 16, 128, 7)] = pk;
      }
    }
  }
  if (coop) { __threadfence(); cg::this_grid().sync(); }

  // ===== phase 2: MFMA attention (R12-proven body) =====
  if (coop || phase == 2) {
    if (!coop || blk < 40) {
      const float4* kp =
          (const float4*)(K + ((size_t)(b_att * L_ + kc * KCH_ + tid) * H_ + h_att) * D_);
      #pragma unroll
      for (int c = 0; c < 8; ++c) {
        float4 a = kp[2 * c], bb = kp[2 * c + 1];
        uint4 pk;
        pk.x = f2bf(a.x) | ((unsigned)f2bf(a.y) << 16);
        pk.y = f2bf(a.z) | ((unsigned)f2bf(a.w) << 16);
        pk.z = f2bf(bb.x) | ((unsigned)f2bf(bb.y) << 16);
        pk.w = f2bf(bb.z) | ((unsigned)f2bf(bb.w) << 16);
        *(uint4*)&Ks[swz_us(tid, c * 16, 128, 7)] = pk;
      }
    }
    if (tid < 48) cut[tid] = (tid < S_) ? mtop[bh_att * S_ + tid] : -1;
    __syncthreads();
    for (int i = tid; i < 48 * 8; i += 256) {
      int row = i >> 3, c = i & 7;
      uint4 pk = make_uint4(0, 0, 0, 0);
      if (row < S_) {
        const float4* qp =
            (const float4*)(Q + ((size_t)(b_att * L_ + cut[row]) * H_ + h_att) * D_);
        float4 a = qp[2 * c], bb = qp[2 * c + 1];
        pk.x = f2bf(a.x) | ((unsigned)f2bf(a.y) << 16);
        pk.y = f2bf(a.z) | ((unsigned)f2bf(a.w) << 16);
        pk.z = f2bf(bb.x) | ((unsigned)f2bf(bb.y) << 16);
        pk.w = f2bf(bb.z) | ((unsigned)f2bf(bb.w) << 16);
      }
      *(uint4*)&Qs[swz_us(row, c * 16, 128, 7)] = pk;
    }
    __syncthreads();

    int l15 = lane & 15, l4 = lane >> 4;
    float4v accS[3][4];
    #pragma unroll
    for (int mt = 0; mt < 3; ++mt)
      #pragma unroll
      for (int nt = 0; nt < 4; ++nt)
        accS[mt][nt] = (float4v){0.f, 0.f, 0.f, 0.f};
    #pragma unroll
    for (int ks = 0; ks < 2; ++ks) {
      short8 afr[3];
      #pragma unroll
      for (int mt = 0; mt < 3; ++mt)
        afr[mt] = *(const short8*)&Qs[swz_us(mt * 16 + l15, ks * 64 + l4 * 16, 128, 7)];
      #pragma unroll
      for (int nt = 0; nt < 4; ++nt) {
        short8 bfr = *(const short8*)
            &Ks[swz_us(w * 64 + nt * 16 + l15, ks * 64 + l4 * 16, 128, 7)];
        #pragma unroll
        for (int mt = 0; mt < 3; ++mt)
          accS[mt][nt] = __builtin_amdgcn_mfma_f32_16x16x32_bf16(
              afr[mt], bfr, accS[mt][nt], 0, 0, 0);
      }
    }

    #pragma unroll
    for (int mt = 0; mt < 3; ++mt) {
      #pragma unroll
      for (int j = 0; j < 4; ++j) {
        int row = mt * 16 + l4 * 4 + j;
        int ct = cut[row];
        float rs = 0.f;
        #pragma unroll
        for (int nt = 0; nt < 4; ++nt) {
          int col = w * 64 + nt * 16 + l15;
          int kg = kc * KCH_ + col;
          float e = (kg <= ct) ? __expf(accS[mt][nt][j] * SCALE) : 0.f;
          rs += e;
          Ps[swz_us(row, col * 2, 512, 15)] = f2bf(e);
        }
        rs += __shfl_xor(rs, 1, 64);
        rs += __shfl_xor(rs, 2, 64);
        rs += __shfl_xor(rs, 4, 64);
        rs += __shfl_xor(rs, 8, 64);
        if (l15 == 0) lred[w][row] = rs;
      }
    }
    __syncthreads();

    if (tid < S_)
      lpart[((size_t)(bh_att * KC_ + kc)) * S_ + tid] =
          lred[0][tid] + lred[1][tid] + lred[2][tid] + lred[3][tid];

    {
      const float4* vp =
          (const float4*)(V + ((size_t)(b_att * L_ + kc * KCH_ + tid) * H_ + h_att) * D_);
      #pragma unroll
      for (int c = 0; c < 16; ++c) {
        float4 v = vp[c];
        int d0 = c * 4;
        Ks[swz_us(d0 + 0, tid * 2, 512, 15)] = f2bf(v.x);
        Ks[swz_us(d0 + 1, tid * 2, 512, 15)] = f2bf(v.y);
        Ks[swz_us(d0 + 2, tid * 2, 512, 15)] = f2bf(v.z);
        Ks[swz_us(d0 + 3, tid * 2, 512, 15)] = f2bf(v.w);
      }
    }
    __syncthreads();

    float4v accU[3];
    #pragma unroll
    for (int i = 0; i < 3; ++i) accU[i] = (float4v){0.f, 0.f, 0.f, 0.f};
    #pragma unroll
    for (int ks = 0; ks < 8; ++ks) {
      #pragma unroll
      for (int i = 0; i < 3; ++i) {
        int pi = w * 3 + i, mt = pi >> 2, nt = pi & 3;
        short8 afr = *(const short8*)
            &Ps[swz_us(mt * 16 + l15, ks * 64 + l4 * 16, 512, 15)];
        short8 bfr = *(const short8*)
            &Ks[swz_us(nt * 16 + l15, ks * 64 + l4 * 16, 512, 15)];
        accU[i] = __builtin_amdgcn_mfma_f32_16x16x32_bf16(afr, bfr, accU[i], 0, 0, 0);
      }
    }
    float* up = updp + ((size_t)(bh_att * KC_ + kc)) * (S_ * D_);
    #pragma unroll
    for (int i = 0; i < 3; ++i) {
      int pi = w * 3 + i, mt = pi >> 2, nt = pi & 3;
      #pragma unroll
      for (int j = 0; j < 4; ++j) {
        int row = mt * 16 + l4 * 4 + j;
        if (row < S_) up[row * D_ + nt * 16 + l15] = accU[i][j];
      }
    }
  }
  if (coop) { __threadfence(); cg::this_grid().sync(); }

  // ===== phase 3: cumsum write (skip scatter rows) + finalize =====
  if (coop || phase == 3) {
    unsigned* bits = (unsigned*)cut;   // 8 uints, cut free after phase 2
    int bh = blk >> 4, cg2 = blk & 15;
    int base = cg2 * 256;
    if (tid < 8) bits[tid] = 0u;
    __syncthreads();
    if (tid < S_) {
      int r = mtop[bh * S_ + tid] - base;
      if ((unsigned)r < 256u) atomicOr(&bits[r >> 5], 1u << (r & 31));
    }
    __syncthreads();

    int b = bh >> 3, h = bh & 7;
    int t = lane & 15, rg = lane >> 4;
    int c = cg2 * 4 + w;
    int l0 = c * 64;
    const float4* V4 = (const float4*)V;
    float4* O4 = (float4*)out;
    float4 carry = ((const float4*)cs)[((size_t)bh * 64 + c) * 16 + t];
    for (int step = 0; step < 16; ++step) {
      int l = l0 + step * 4 + rg;
      float4 v = V4[((size_t)(b * L_ + l) * H_ + h) * 16 + t];
      float4 u;
      u.x = __shfl_up(v.x, 16, 64); u.y = __shfl_up(v.y, 16, 64);
      u.z = __shfl_up(v.z, 16, 64); u.w = __shfl_up(v.w, 16, 64);
      if (rg >= 1) { v.x += u.x; v.y += u.y; v.z += u.z; v.w += u.w; }
      u.x = __shfl_up(v.x, 32, 64); u.y = __shfl_up(v.y, 32, 64);
      u.z = __shfl_up(v.z, 32, 64); u.w = __shfl_up(v.w, 32, 64);
      if (rg >= 2) { v.x += u.x; v.y += u.y; v.z += u.z; v.w += u.w; }
      int wl = l - base;
      if (!((bits[wl >> 5] >> (wl & 31)) & 1u)) {
        float4 o;
        o.x = carry.x + v.x; o.y = carry.y + v.y;
        o.z = carry.z + v.z; o.w = carry.w + v.w;
        O4[((size_t)bh * L_ + l) * 16 + t] = o;
      }
      carry.x += __shfl(v.x, 48 + t, 64); carry.y += __shfl(v.y, 48 + t, 64);
      carry.z += __shfl(v.z, 48 + t, 64); carry.w += __shfl(v.w, 48 + t, 64);
    }

    if (blk < 32) {
      // ---- finalize (R12-proven) ----
      float* linv = (float*)lred;      // overlays, free in phase 3
      int*   mt2  = (int*)(lred) + 64;
      int bhf = blk;
      __syncthreads();
      if (tid < S_) {
        float l = 0.f;
        for (int kcc = 0; kcc < KC_; ++kcc)
          l += lpart[(size_t)(bhf * KC_ + kcc) * S_ + tid];
        linv[tid] = 1.0f / l;
        mt2[tid] = mtop[bhf * S_ + tid];
      }
      __syncthreads();
      for (int i = tid; i < S_ * D_; i += 256) {
        int r = i >> 6, d = i & 63;
        float u = 0.f;
        for (int kcc = 0; kcc < KC_; ++kcc)
          u += updp[((size_t)(bhf * KC_ + kcc)) * (S_ * D_) + i];
        out[((size_t)bhf * L_ + mt2[r]) * D_ + d] = u * linv[r];
      }
    }
  }
}

extern "C" void kernel_launch(void* const* d_in, const int* in_sizes, int n_in,
                              void* d_out, int out_size, void* d_ws, size_t ws_size,
                              hipStream_t stream) {
  const float* Q = (const float*)d_in[0];
  const float* K = (const float*)d_in[1];
  const float* V = (const float*)d_in[2];
  const int*   I = (const int*)d_in[3];
  float* out = (float*)d_out;
  float* ws = (float*)d_ws;

  float* M     = ws;                       // 131072 floats
  float* cs    = ws + 131072;              // 131072 floats
  float* lpart = ws + 262144;              // 32*16*45 = 23040 floats
  float* updp  = ws + 262144 + 23040;      // 32*16*45*64 = 1474560 floats
  int*   mtop  = (int*)(ws + 262144 + 23040 + 1474560);   // 1440 ints

  kA<<<128 * 136, 256, 0, stream>>>(Q, K, V, I, M, cs);

  int ph0 = 0;
  void* args[] = {(void*)&Q, (void*)&K, (void*)&V, (void*)&M, (void*)&cs,
                  (void*)&mtop, (void*)&lpart, (void*)&updp, (void*)&out,
                  (void*)&ph0};
  hipError_t e = hipLaunchCooperativeKernel((void*)kT, dim3(512), dim3(256),
                                            args, 0, stream);
  if (e != hipSuccess) {
    (void)hipGetLastError();
    kT<<<40, 256, 0, stream>>>(Q, K, V, M, cs, mtop, lpart, updp, out, 1);
    kT<<<512, 256, 0, stream>>>(Q, K, V, M, cs, mtop, lpart, updp, out, 2);
    kT<<<512, 256, 0, stream>>>(Q, K, V, M, cs, mtop, lpart, updp, out, 3);
  }
}

// Round 14
// 187.930 us; speedup vs baseline: 2.0241x; 2.0241x over previous
//
#include <hip/hip_runtime.h>
#include <float.h>
#include <math.h>

#define B_ 4
#define L_ 4096
#define H_ 8
#define D_ 64
#define S_ 45      // sample_k == u == 45
#define KC_ 16     // k-chunks for attention pass
#define KCH_ 256   // k per chunk
#define SCALE 0.125f

typedef __attribute__((ext_vector_type(8))) short short8;
typedef __attribute__((ext_vector_type(4))) float float4v;

__device__ __forceinline__ ushort f2bf(float x) {
  unsigned u = __float_as_uint(x);
  return (ushort)((u + 0x7FFFu + ((u >> 16) & 1u)) >> 16);
}

// swizzled ushort index: row-major rows of rowb bytes, 16B slots XORed by row&m
__device__ __forceinline__ int swz_us(int row, int col_b, int rowb, int m) {
  int slot = (col_b >> 4) ^ (row & m);
  return row * (rowb >> 1) + (slot << 3) + ((col_b & 15) >> 1);
}

__device__ __forceinline__ unsigned ordf(float f) {
  unsigned u = __float_as_uint(f);
  return (u & 0x80000000u) ? ~u : (u | 0x80000000u);
}

// ================= kA: 2-head time-phased gather + csum_chunks (R12-proven) ===
// CLOSED: at per-CU vector-memory line-throughput roofline (~23.6M lines,
// ~2.5 cyc/line/CU ~= 100us). Duration invariant to residency/MLP/occupancy.
__global__ __launch_bounds__(256) void kA(
    const float* __restrict__ Q, const float* __restrict__ K,
    const float* __restrict__ V, const int* __restrict__ idxs,
    float* __restrict__ M, float* __restrict__ cs)
{
  int blk = blockIdx.x;
  int grp = blk / 136, within = blk % 136;
  int tid = threadIdx.x;
  int w = tid >> 6, lane = tid & 63;

  if (within >= 128) {
    if (grp >= 64) return;                   // only 512 csum blocks needed
    int cblk = grp * 8 + (within - 128);     // 0..511
    int bh = cblk >> 4, cg = cblk & 15;
    int b = bh >> 3, h = bh & 7;
    int t = lane & 15, rg = lane >> 4;
    int c = cg * 4 + w;
    int l0 = c * 64;
    const float4* V4 = (const float4*)V;
    float4 acc = make_float4(0.f, 0.f, 0.f, 0.f);
    for (int step = 0; step < 16; ++step) {
      int l = l0 + step * 4 + rg;
      float4 v = V4[((size_t)(b * L_ + l) * H_ + h) * 16 + t];
      acc.x += v.x; acc.y += v.y; acc.z += v.z; acc.w += v.w;
    }
    acc.x += __shfl_xor(acc.x, 16, 64); acc.y += __shfl_xor(acc.y, 16, 64);
    acc.z += __shfl_xor(acc.z, 16, 64); acc.w += __shfl_xor(acc.w, 16, 64);
    acc.x += __shfl_xor(acc.x, 32, 64); acc.y += __shfl_xor(acc.y, 32, 64);
    acc.z += __shfl_xor(acc.z, 32, 64); acc.w += __shfl_xor(acc.w, 32, 64);
    if (rg == 0)
      ((float4*)cs)[((size_t)bh * 64 + c) * 16 + t] = acc;
    return;
  }

  // ---- gather ----
  int kblk = grp * 128 + within;        // 0..16383; kblk%8 == blk%8 (XCD pin)
  int phase = kblk >> 13;               // 0: b in {0,1}; 1: b in {2,3}
  int pblk = kblk & 8191;
  int g = pblk & 7;                     // XCD-pinned group within phase
  int b = (g >> 2) + phase * 2;
  int hq = g & 3;                       // head pair hq*2, hq*2+1
  int chunk = pblk >> 3;                // 0..1023
  int l = chunk * 4 + w;                // this wave's query
  int t31 = lane & 31;
  int half = lane >> 5;

  const float4* qp =
      (const float4*)(Q + ((size_t)(b * L_ + l) * H_ + hq * 2) * D_);
  float4 qv = qp[t31];

  int s = lane < S_ ? lane : S_ - 1;
  int idxall = idxs[l * S_ + s];

  float vmax = -FLT_MAX, vsum = 0.f;
  #pragma unroll
  for (int c = 0; c < 3; ++c) {
    int kidx[6];
    #pragma unroll
    for (int jj = 0; jj < 6; ++jj)
      kidx[jj] = __shfl(idxall, (c * 6 + jj) * 2 + half, 64);
    float4 kv[6];
    #pragma unroll
    for (int jj = 0; jj < 6; ++jj)
      kv[jj] = ((const float4*)(K +
          ((size_t)(b * L_ + kidx[jj]) * H_ + hq * 2) * D_))[t31];
    #pragma unroll
    for (int jj = 0; jj < 6; ++jj) {
      float p = qv.x * kv[jj].x;
      p = fmaf(qv.y, kv[jj].y, p);
      p = fmaf(qv.z, kv[jj].z, p);
      p = fmaf(qv.w, kv[jj].w, p);
      p += __shfl_xor(p, 1, 64);
      p += __shfl_xor(p, 2, 64);
      p += __shfl_xor(p, 4, 64);
      p += __shfl_xor(p, 8, 64);
      vmax = fmaxf(vmax, p);
      vsum += p;
    }
  }
  {
    int kidx[5];
    #pragma unroll
    for (int jj = 0; jj < 5; ++jj) {
      int s2 = (18 + jj) * 2 + half;          // 36..45
      kidx[jj] = __shfl(idxall, s2 > 44 ? 44 : s2, 64);
    }
    float4 kv[5];
    #pragma unroll
    for (int jj = 0; jj < 5; ++jj)
      kv[jj] = ((const float4*)(K +
          ((size_t)(b * L_ + kidx[jj]) * H_ + hq * 2) * D_))[t31];
    #pragma unroll
    for (int jj = 0; jj < 5; ++jj) {
      float p = qv.x * kv[jj].x;
      p = fmaf(qv.y, kv[jj].y, p);
      p = fmaf(qv.z, kv[jj].z, p);
      p = fmaf(qv.w, kv[jj].w, p);
      p += __shfl_xor(p, 1, 64);
      p += __shfl_xor(p, 2, 64);
      p += __shfl_xor(p, 4, 64);
      p += __shfl_xor(p, 8, 64);
      bool dup = (jj == 4) && (half == 1);    // sample 45 -> clamped dup
      vmax = fmaxf(vmax, p);
      if (!dup) vsum += p;
    }
  }
  vmax = fmaxf(vmax, __shfl_xor(vmax, 32, 64));
  vsum += __shfl_xor(vsum, 32, 64);
  if ((lane & 15) == 0 && half == 0) {
    int h = hq * 2 + (lane >> 4);
    M[(size_t)(b * H_ + h) * L_ + l] = vmax - vsum * (1.0f / L_);
  }
}

// ================= kB: top-45 per (b,h) + csum_scan (R12-proven) ==============
__global__ __launch_bounds__(256) void kB(
    const float* __restrict__ M, int* __restrict__ mtop, float* __restrict__ cs)
{
  int blk = blockIdx.x;
  int tid = threadIdx.x;
  if (blk >= 32) {
    int g = (blk - 32) * 256 + tid;    // 2048 threads total
    int bh = g >> 6, d = g & 63;
    float v[64];
    #pragma unroll
    for (int c = 0; c < 64; ++c) v[c] = cs[((size_t)bh * 64 + c) * D_ + d];
    float run = 0.f;
    #pragma unroll
    for (int c = 0; c < 64; ++c) {
      float a = v[c];
      cs[((size_t)bh * 64 + c) * D_ + d] = run;
      run += a;
    }
    return;
  }
  __shared__ unsigned long long cand[4][S_];
  int bh = blk;
  int w = tid >> 6, lane = tid & 63;
  const float* Mp = M + (size_t)bh * L_;
  unsigned long long key[16];
  #pragma unroll
  for (int j = 0; j < 16; ++j) {
    int gi = w * 1024 + j * 64 + lane;
    key[j] = ((unsigned long long)ordf(Mp[gi]) << 32) | (unsigned)(~gi);
  }
  for (int it = 0; it < S_; ++it) {
    unsigned long long loc = key[0];
    #pragma unroll
    for (int j = 1; j < 16; ++j) loc = key[j] > loc ? key[j] : loc;
    unsigned long long best = loc;
    #pragma unroll
    for (int m = 32; m >= 1; m >>= 1) {
      unsigned long long o = __shfl_xor(best, m, 64);
      best = o > best ? o : best;
    }
    if (loc == best) {
      #pragma unroll
      for (int j = 0; j < 16; ++j) if (key[j] == best) key[j] = 0ull;
    }
    if (lane == 0) cand[w][it] = best;
  }
  __syncthreads();
  if (w == 0) {
    unsigned long long k2[3];
    #pragma unroll
    for (int j = 0; j < 3; ++j) {
      int c = j * 64 + lane;
      k2[j] = (c < 4 * S_) ? cand[c / S_][c % S_] : 0ull;
    }
    for (int it = 0; it < S_; ++it) {
      unsigned long long loc = k2[0];
      loc = k2[1] > loc ? k2[1] : loc;
      loc = k2[2] > loc ? k2[2] : loc;
      unsigned long long best = loc;
      #pragma unroll
      for (int m = 32; m >= 1; m >>= 1) {
        unsigned long long o = __shfl_xor(best, m, 64);
        best = o > best ? o : best;
      }
      if (loc == best) {
        #pragma unroll
        for (int j = 0; j < 3; ++j) if (k2[j] == best) k2[j] = 0ull;
      }
      if (lane == 0) mtop[bh * S_ + it] = (int)(~(unsigned)(best & 0xFFFFFFFFu));
    }
  }
}

// ================= kAW: MFMA attention fused with cumsum-write ================
// Groups of 16 blocks: 8 attn + 8 write (both %8==blk%8 -> XCD pins preserved).
// Attn body = R12-proven kATT + T14 async-stage of V (regs early, LDS late).
// Write body = R12-proven bitmap-skip cumsum write.
__global__ __launch_bounds__(256) void kAW(
    const float* __restrict__ Q, const float* __restrict__ K,
    const float* __restrict__ V, const float* __restrict__ cs,
    const int* __restrict__ mtop, float* __restrict__ lpart,
    float* __restrict__ updp, float* __restrict__ out)
{
  __shared__ __align__(16) ushort Ks[256 * 64];   // 32 KB; reused as Vt[64][256]
  __shared__ __align__(16) ushort Qs[48 * 64];    // 6 KB
  __shared__ __align__(16) ushort Ps[48 * 256];   // 24 KB
  __shared__ float lred[4][48];
  __shared__ int   cut[48];
  __shared__ unsigned bits[8];

  int blk = blockIdx.x;
  int grp = blk >> 4, within = blk & 15;
  int tid = threadIdx.x;
  int w = tid >> 6, lane = tid & 63;

  if (within >= 8) {
    // ---- cumsum write with scatter-row skip (R12-proven) ----
    int wblk = grp * 8 + (within - 8);   // 0..511
    int bh = wblk >> 4, cg2 = wblk & 15;
    int base = cg2 * 256;
    if (tid < 8) bits[tid] = 0u;
    __syncthreads();
    if (tid < S_) {
      int r = mtop[bh * S_ + tid] - base;
      if ((unsigned)r < 256u) atomicOr(&bits[r >> 5], 1u << (r & 31));
    }
    __syncthreads();

    int b = bh >> 3, h = bh & 7;
    int t = lane & 15, rg = lane >> 4;
    int c = cg2 * 4 + w;
    int l0 = c * 64;
    const float4* V4 = (const float4*)V;
    float4* O4 = (float4*)out;
    float4 carry = ((const float4*)cs)[((size_t)bh * 64 + c) * 16 + t];
    for (int step = 0; step < 16; ++step) {
      int l = l0 + step * 4 + rg;
      float4 v = V4[((size_t)(b * L_ + l) * H_ + h) * 16 + t];
      float4 u;
      u.x = __shfl_up(v.x, 16, 64); u.y = __shfl_up(v.y, 16, 64);
      u.z = __shfl_up(v.z, 16, 64); u.w = __shfl_up(v.w, 16, 64);
      if (rg >= 1) { v.x += u.x; v.y += u.y; v.z += u.z; v.w += u.w; }
      u.x = __shfl_up(v.x, 32, 64); u.y = __shfl_up(v.y, 32, 64);
      u.z = __shfl_up(v.z, 32, 64); u.w = __shfl_up(v.w, 32, 64);
      if (rg >= 2) { v.x += u.x; v.y += u.y; v.z += u.z; v.w += u.w; }
      int wl = l - base;
      if (!((bits[wl >> 5] >> (wl & 31)) & 1u)) {
        float4 o;
        o.x = carry.x + v.x; o.y = carry.y + v.y;
        o.z = carry.z + v.z; o.w = carry.w + v.w;
        O4[((size_t)bh * L_ + l) * 16 + t] = o;
      }
      carry.x += __shfl(v.x, 48 + t, 64); carry.y += __shfl(v.y, 48 + t, 64);
      carry.z += __shfl(v.z, 48 + t, 64); carry.w += __shfl(v.w, 48 + t, 64);
    }
    return;
  }

  // ---- MFMA attention partials (R12-proven + V async-stage) ----
  int ablk = grp * 8 + within;            // 0..511; ablk%8 == blk%8
  int kc = ablk >> 5;
  int r5 = ablk & 31;
  int bh = ((r5 & 7) << 2) | (r5 >> 3);   // bh>>2 == ablk&7 -> XCD pin
  int b = bh >> 3, h = bh & 7;
  int l15 = lane & 15, l4 = lane >> 4;

  // T14: issue V loads early -> overlap with K/Q staging fetch
  float4 vreg[16];
  {
    const float4* vp =
        (const float4*)(V + ((size_t)(b * L_ + kc * KCH_ + tid) * H_ + h) * D_);
    #pragma unroll
    for (int c = 0; c < 16; ++c) vreg[c] = vp[c];
  }

  if (tid < 48) cut[tid] = (tid < S_) ? mtop[bh * S_ + tid] : -1;
  __syncthreads();

  {
    const float4* kp =
        (const float4*)(K + ((size_t)(b * L_ + kc * KCH_ + tid) * H_ + h) * D_);
    #pragma unroll
    for (int c = 0; c < 8; ++c) {
      float4 a = kp[2 * c], bb = kp[2 * c + 1];
      uint4 pk;
      pk.x = f2bf(a.x) | ((unsigned)f2bf(a.y) << 16);
      pk.y = f2bf(a.z) | ((unsigned)f2bf(a.w) << 16);
      pk.z = f2bf(bb.x) | ((unsigned)f2bf(bb.y) << 16);
      pk.w = f2bf(bb.z) | ((unsigned)f2bf(bb.w) << 16);
      *(uint4*)&Ks[swz_us(tid, c * 16, 128, 7)] = pk;
    }
  }
  for (int i = tid; i < 48 * 8; i += 256) {
    int row = i >> 3, c = i & 7;
    uint4 pk = make_uint4(0, 0, 0, 0);
    if (row < S_) {
      const float4* qp =
          (const float4*)(Q + ((size_t)(b * L_ + cut[row]) * H_ + h) * D_);
      float4 a = qp[2 * c], bb = qp[2 * c + 1];
      pk.x = f2bf(a.x) | ((unsigned)f2bf(a.y) << 16);
      pk.y = f2bf(a.z) | ((unsigned)f2bf(a.w) << 16);
      pk.z = f2bf(bb.x) | ((unsigned)f2bf(bb.y) << 16);
      pk.w = f2bf(bb.z) | ((unsigned)f2bf(bb.w) << 16);
    }
    *(uint4*)&Qs[swz_us(row, c * 16, 128, 7)] = pk;
  }
  __syncthreads();

  float4v accS[3][4];
  #pragma unroll
  for (int mt = 0; mt < 3; ++mt)
    #pragma unroll
    for (int nt = 0; nt < 4; ++nt)
      accS[mt][nt] = (float4v){0.f, 0.f, 0.f, 0.f};
  #pragma unroll
  for (int ks = 0; ks < 2; ++ks) {
    short8 afr[3];
    #pragma unroll
    for (int mt = 0; mt < 3; ++mt)
      afr[mt] = *(const short8*)&Qs[swz_us(mt * 16 + l15, ks * 64 + l4 * 16, 128, 7)];
    #pragma unroll
    for (int nt = 0; nt < 4; ++nt) {
      short8 bfr = *(const short8*)
          &Ks[swz_us(w * 64 + nt * 16 + l15, ks * 64 + l4 * 16, 128, 7)];
      #pragma unroll
      for (int mt = 0; mt < 3; ++mt)
        accS[mt][nt] = __builtin_amdgcn_mfma_f32_16x16x32_bf16(
            afr[mt], bfr, accS[mt][nt], 0, 0, 0);
    }
  }

  #pragma unroll
  for (int mt = 0; mt < 3; ++mt) {
    #pragma unroll
    for (int j = 0; j < 4; ++j) {
      int row = mt * 16 + l4 * 4 + j;
      int ct = cut[row];
      float rs = 0.f;
      #pragma unroll
      for (int nt = 0; nt < 4; ++nt) {
        int col = w * 64 + nt * 16 + l15;
        int kg = kc * KCH_ + col;
        float e = (kg <= ct) ? __expf(accS[mt][nt][j] * SCALE) : 0.f;
        rs += e;
        Ps[swz_us(row, col * 2, 512, 15)] = f2bf(e);
      }
      rs += __shfl_xor(rs, 1, 64);
      rs += __shfl_xor(rs, 2, 64);
      rs += __shfl_xor(rs, 4, 64);
      rs += __shfl_xor(rs, 8, 64);
      if (l15 == 0) lred[w][row] = rs;
    }
  }
  __syncthreads();

  if (tid < S_)
    lpart[((size_t)(bh * KC_ + kc)) * S_ + tid] =
        lred[0][tid] + lred[1][tid] + lred[2][tid] + lred[3][tid];

  // V-stage: registers -> LDS (no global access here)
  #pragma unroll
  for (int c = 0; c < 16; ++c) {
    float4 v = vreg[c];
    int d0 = c * 4;
    Ks[swz_us(d0 + 0, tid * 2, 512, 15)] = f2bf(v.x);
    Ks[swz_us(d0 + 1, tid * 2, 512, 15)] = f2bf(v.y);
    Ks[swz_us(d0 + 2, tid * 2, 512, 15)] = f2bf(v.z);
    Ks[swz_us(d0 + 3, tid * 2, 512, 15)] = f2bf(v.w);
  }
  __syncthreads();

  float4v accU[3];
  #pragma unroll
  for (int i = 0; i < 3; ++i) accU[i] = (float4v){0.f, 0.f, 0.f, 0.f};
  #pragma unroll
  for (int ks = 0; ks < 8; ++ks) {
    #pragma unroll
    for (int i = 0; i < 3; ++i) {
      int pi = w * 3 + i, mt = pi >> 2, nt = pi & 3;
      short8 afr = *(const short8*)
          &Ps[swz_us(mt * 16 + l15, ks * 64 + l4 * 16, 512, 15)];
      short8 bfr = *(const short8*)
          &Ks[swz_us(nt * 16 + l15, ks * 64 + l4 * 16, 512, 15)];
      accU[i] = __builtin_amdgcn_mfma_f32_16x16x32_bf16(afr, bfr, accU[i], 0, 0, 0);
    }
  }
  float* up = updp + ((size_t)(bh * KC_ + kc)) * (S_ * D_);
  #pragma unroll
  for (int i = 0; i < 3; ++i) {
    int pi = w * 3 + i, mt = pi >> 2, nt = pi & 3;
    #pragma unroll
    for (int j = 0; j < 4; ++j) {
      int row = mt * 16 + l4 * 4 + j;
      if (row < S_) up[row * D_ + nt * 16 + l15] = accU[i][j];
    }
  }
}

// ================= kFin: reduce partials, normalize, scatter ==================
__global__ __launch_bounds__(256) void kFin(
    const float* __restrict__ lpart, const float* __restrict__ updp,
    const int* __restrict__ mtop, float* __restrict__ out)
{
  __shared__ float linv[S_];
  __shared__ int   mt[S_];
  int bh = blockIdx.x;
  int tid = threadIdx.x;
  if (tid < S_) {
    float l = 0.f;
    for (int kc = 0; kc < KC_; ++kc) l += lpart[(size_t)(bh * KC_ + kc) * S_ + tid];
    linv[tid] = 1.0f / l;
    mt[tid] = mtop[bh * S_ + tid];
  }
  __syncthreads();
  for (int i = tid; i < S_ * D_; i += 256) {
    int r = i >> 6, d = i & 63;
    float u = 0.f;
    for (int kc = 0; kc < KC_; ++kc) u += updp[((size_t)(bh * KC_ + kc)) * (S_ * D_) + i];
    out[((size_t)bh * L_ + mt[r]) * D_ + d] = u * linv[r];
  }
}

extern "C" void kernel_launch(void* const* d_in, const int* in_sizes, int n_in,
                              void* d_out, int out_size, void* d_ws, size_t ws_size,
                              hipStream_t stream) {
  const float* Q = (const float*)d_in[0];
  const float* K = (const float*)d_in[1];
  const float* V = (const float*)d_in[2];
  const int*   I = (const int*)d_in[3];
  float* out = (float*)d_out;
  float* ws = (float*)d_ws;

  float* M     = ws;                       // 131072 floats
  float* cs    = ws + 131072;              // 131072 floats
  float* lpart = ws + 262144;              // 32*16*45 = 23040 floats
  float* updp  = ws + 262144 + 23040;      // 32*16*45*64 = 1474560 floats
  int*   mtop  = (int*)(ws + 262144 + 23040 + 1474560);   // 1440 ints

  kA<<<128 * 136, 256, 0, stream>>>(Q, K, V, I, M, cs);
  kB<<<40, 256, 0, stream>>>(M, mtop, cs);
  kAW<<<64 * 16, 256, 0, stream>>>(Q, K, V, cs, mtop, lpart, updp, out);
  kFin<<<B_ * H_, 256, 0, stream>>>(lpart, updp, mtop, out);
}